// Round 1
// baseline (252.764 us; speedup 1.0000x reference)
//
#include <hip/hip_runtime.h>

typedef short  s16x8 __attribute__((ext_vector_type(8)));   // 8 bf16 (bit patterns)
typedef float  f32x4 __attribute__((ext_vector_type(4)));
typedef unsigned short u16;

#define DEVI static __device__ __forceinline__

constexpr int T_  = 128;
constexpr int F_  = 14;
constexpr int H_  = 64;
constexpr int BPB = 16;   // batch rows per block
constexpr int PIT = 72;   // h row pitch in ushorts (144 B, 16B-aligned, conflict-friendly)

DEVI u16 f2bf(float f) {                     // fp32 -> bf16 bits, RNE
  unsigned int u = __builtin_bit_cast(unsigned int, f);
  u += 0x7fffu + ((u >> 16) & 1u);
  return (u16)(u >> 16);
}
DEVI float bf2f(u16 s) {
  unsigned int u = ((unsigned int)s) << 16;
  return __builtin_bit_cast(float, u);
}
DEVI float tanhfast(float x) {
  // tanh(x) = 2/(1+2^(-2*log2e*x)) - 1 ; |x| <= ~24 structurally -> no overflow
  float e = exp2f(x * -2.8853900817779268f);
  float r = __builtin_amdgcn_rcpf(1.0f + e);
  return __builtin_fmaf(2.0f, r, -1.0f);
}
DEVI f32x4 MFMA(s16x8 a, s16x8 b, f32x4 c) {
  return __builtin_amdgcn_mfma_f32_16x16x32_bf16(a, b, c, 0, 0, 0);
}

// A-frag loader: 8 contiguous fp32 (16B-aligned) -> bf16 frag. Wrow = W + j*64.
DEVI s16x8 ldw8(const float* Wrow, int koff) {
  const f32x4 a = *(const f32x4*)(Wrow + koff);
  const f32x4 b = *(const f32x4*)(Wrow + koff + 4);
  s16x8 r;
  r[0] = (short)f2bf(a[0]); r[1] = (short)f2bf(a[1]);
  r[2] = (short)f2bf(a[2]); r[3] = (short)f2bf(a[3]);
  r[4] = (short)f2bf(b[0]); r[5] = (short)f2bf(b[1]);
  r[6] = (short)f2bf(b[2]); r[7] = (short)f2bf(b[3]);
  return r;
}

__global__ __launch_bounds__(256) void rnn_fused(
    const float* __restrict__ x,
    const float* __restrict__ Wih0, const float* __restrict__ Whh0,
    const float* __restrict__ bih0, const float* __restrict__ bhh0,
    const float* __restrict__ Wih1, const float* __restrict__ Whh1,
    const float* __restrict__ bih1, const float* __restrict__ bhh1,
    const float* __restrict__ Wih2, const float* __restrict__ Whh2,
    const float* __restrict__ bih2, const float* __restrict__ bhh2,
    const float* __restrict__ fc1w, const float* __restrict__ fc1b,
    const float* __restrict__ fc2w, const float* __restrict__ fc2b,
    float* __restrict__ out)
{
  // h state, bf16 bits, double buffered: [buf][layer][batch][hid(+pad)]
  __shared__ __align__(16) u16 hls[2][3][BPB][PIT];

  const int tid  = threadIdx.x;
  const int w    = tid >> 6;        // wave id = hid M-tile (0..3)
  const int lane = tid & 63;
  const int m    = lane & 15;       // batch col (B-frag/D col) AND A-frag row-in-tile
  const int g    = lane >> 4;       // k-group / D row group
  const int b0   = blockIdx.x * BPB;

  { // zero LDS (only buf0 strictly needed; do all)
    int* p = (int*)&hls[0][0][0][0];
    const int nwords = (int)(sizeof(hls) / 4);
    for (int i = tid; i < nwords; i += 256) p[i] = 0;
  }

  // ---- static weight A-fragments (A[j][k] row-major, j = 16w + m) ----
  const int j = 16 * w + m;
  s16x8 A0[3], A1[4], A2[4];
  { // layer0 kt=0: W_ih0 row j, 14 wide, zero-padded to k=32
    s16x8 r;
    if (g == 0) {
      const float* p = Wih0 + j * F_;
      #pragma unroll
      for (int i = 0; i < 8; i++) r[i] = (short)f2bf(p[i]);
    } else if (g == 1) {
      const float* p = Wih0 + j * F_;
      #pragma unroll
      for (int i = 0; i < 6; i++) r[i] = (short)f2bf(p[8 + i]);
      r[6] = 0; r[7] = 0;
    } else {
      #pragma unroll
      for (int i = 0; i < 8; i++) r[i] = 0;
    }
    A0[0] = r;
  }
  A0[1] = ldw8(Whh0 + j * H_, 8 * g);
  A0[2] = ldw8(Whh0 + j * H_, 32 + 8 * g);
  #pragma unroll
  for (int kt = 0; kt < 2; kt++) {
    A1[kt]     = ldw8(Wih1 + j * H_, 32 * kt + 8 * g);
    A1[kt + 2] = ldw8(Whh1 + j * H_, 32 * kt + 8 * g);
    A2[kt]     = ldw8(Wih2 + j * H_, 32 * kt + 8 * g);
    A2[kt + 2] = ldw8(Whh2 + j * H_, 32 * kt + 8 * g);
  }

  // biases: D row jr = 16w + 4g + r ; combined b_ih + b_hh
  f32x4 bc0, bc1, bc2;
  #pragma unroll
  for (int r = 0; r < 4; r++) {
    int jr = 16 * w + 4 * g + r;
    bc0[r] = bih0[jr] + bhh0[jr];
    bc1[r] = bih1[jr] + bhh1[jr];
    bc2[r] = bih2[jr] + bhh2[jr];
  }

  __syncthreads();  // LDS zero visible

  const float* xrow = x + (size_t)(b0 + m) * T_ * F_;
  auto load_x = [&](int t) -> s16x8 {   // B-frag: x[batch=m][k=8g+i], pad >=14 with 0
    s16x8 r;
    const float* p = xrow + t * F_;
    if (g == 0) {
      #pragma unroll
      for (int i = 0; i < 8; i++) r[i] = (short)f2bf(p[i]);
    } else if (g == 1) {
      #pragma unroll
      for (int i = 0; i < 6; i++) r[i] = (short)f2bf(p[8 + i]);
      r[6] = 0; r[7] = 0;
    } else {
      #pragma unroll
      for (int i = 0; i < 8; i++) r[i] = 0;
    }
    return r;
  };
  auto ldh = [&](int buf, int l, int koff) -> s16x8 {  // B-frag: h[batch=m][koff..+7]
    return *(const s16x8*)&hls[buf][l][m][koff];
  };
  auto sth = [&](int buf, int l, const f32x4& v) {     // D: 4 contiguous hid @ row m
    unsigned int lo = (unsigned int)f2bf(v[0]) | ((unsigned int)f2bf(v[1]) << 16);
    unsigned int hi = (unsigned int)f2bf(v[2]) | ((unsigned int)f2bf(v[3]) << 16);
    uint2 u; u.x = lo; u.y = hi;
    *(uint2*)&hls[buf][l][m][16 * w + 4 * g] = u;
  };

  s16x8 bx = load_x(0);
  for (int t = 0; t < T_; t++) {
    const int p = t & 1, q = p ^ 1;
    s16x8 bxn = load_x(t + 1 < T_ ? t + 1 : T_ - 1);  // prefetch (clamped, no OOB)

    // ---- layer 0: pre^T = A0 * [x ; h0_old]
    f32x4 acc = bc0;
    acc = MFMA(A0[0], bx, acc);
    acc = MFMA(A0[1], ldh(p, 0, 8 * g), acc);
    acc = MFMA(A0[2], ldh(p, 0, 32 + 8 * g), acc);
    f32x4 hv;
    #pragma unroll
    for (int r = 0; r < 4; r++) hv[r] = tanhfast(acc[r]);
    sth(q, 0, hv);
    __syncthreads();

    // ---- layer 1: inputs h0_new (buf q), h1_old (buf p)
    acc = bc1;
    acc = MFMA(A1[0], ldh(q, 0, 8 * g), acc);
    acc = MFMA(A1[1], ldh(q, 0, 32 + 8 * g), acc);
    acc = MFMA(A1[2], ldh(p, 1, 8 * g), acc);
    acc = MFMA(A1[3], ldh(p, 1, 32 + 8 * g), acc);
    #pragma unroll
    for (int r = 0; r < 4; r++) hv[r] = tanhfast(acc[r]);
    sth(q, 1, hv);
    __syncthreads();

    // ---- layer 2
    acc = bc2;
    acc = MFMA(A2[0], ldh(q, 1, 8 * g), acc);
    acc = MFMA(A2[1], ldh(q, 1, 32 + 8 * g), acc);
    acc = MFMA(A2[2], ldh(p, 2, 8 * g), acc);
    acc = MFMA(A2[3], ldh(p, 2, 32 + 8 * g), acc);
    #pragma unroll
    for (int r = 0; r < 4; r++) hv[r] = tanhfast(acc[r]);
    sth(q, 2, hv);
    __syncthreads();

    bx = bxn;
  }

  // ---- FC head, wave 0 only. Final h2 is in buf 0 (T even). lane=(m, g): fc1 j=8g..8g+7
  if (w == 0) {
    float hr[64];
    #pragma unroll
    for (int kt = 0; kt < 8; kt++) {
      s16x8 hb = *(const s16x8*)&hls[0][2][m][kt * 8];
      #pragma unroll
      for (int i = 0; i < 8; i++) hr[kt * 8 + i] = bf2f((u16)hb[i]);
    }
    float acc2 = 0.f;
    #pragma unroll
    for (int jj = 0; jj < 8; jj++) {
      const int jf = 8 * g + jj;
      float s = fc1b[jf];
      const f32x4* wp = (const f32x4*)(fc1w + jf * H_);
      #pragma unroll
      for (int kq = 0; kq < 16; kq++) {
        f32x4 wv = wp[kq];
        s += hr[4 * kq + 0] * wv[0] + hr[4 * kq + 1] * wv[1]
           + hr[4 * kq + 2] * wv[2] + hr[4 * kq + 3] * wv[3];
      }
      s = fmaxf(s, 0.f);
      acc2 += s * fc2w[jf];
    }
    acc2 += __shfl_xor(acc2, 16, 64);
    acc2 += __shfl_xor(acc2, 32, 64);
    if (lane < 16) out[b0 + m] = acc2 + fc2b[0];
  }
}

extern "C" void kernel_launch(void* const* d_in, const int* in_sizes, int n_in,
                              void* d_out, int out_size, void* d_ws, size_t ws_size,
                              hipStream_t stream) {
  const float* x    = (const float*)d_in[0];
  const float* Wih0 = (const float*)d_in[1];
  const float* Whh0 = (const float*)d_in[2];
  const float* bih0 = (const float*)d_in[3];
  const float* bhh0 = (const float*)d_in[4];
  const float* Wih1 = (const float*)d_in[5];
  const float* Whh1 = (const float*)d_in[6];
  const float* bih1 = (const float*)d_in[7];
  const float* bhh1 = (const float*)d_in[8];
  const float* Wih2 = (const float*)d_in[9];
  const float* Whh2 = (const float*)d_in[10];
  const float* bih2 = (const float*)d_in[11];
  const float* bhh2 = (const float*)d_in[12];
  const float* fc1w = (const float*)d_in[13];
  const float* fc1b = (const float*)d_in[14];
  const float* fc2w = (const float*)d_in[15];
  const float* fc2b = (const float*)d_in[16];

  rnn_fused<<<dim3(4096 / BPB), dim3(256), 0, stream>>>(
      x, Wih0, Whh0, bih0, bhh0, Wih1, Whh1, bih1, bhh1,
      Wih2, Whh2, bih2, bhh2, fc1w, fc1b, fc2w, fc2b, (float*)d_out);
}